// Round 7
// baseline (259.551 us; speedup 1.0000x reference)
//
#include <hip/hip_runtime.h>
#include <hip/hip_bf16.h>
#include <math.h>

// Problem constants
#define B_   2
#define S_   2048
#define DM_  1024
#define H_   16
#define HD_  64
#define MEM_ 1000
#define KTOT 10
#define NROW (B_ * S_)          // 4096
#define NEG9 (-1e9f)
#define LDK  72                 // bf16 row stride in attention LDS tiles
#define QITEMS 180              // units per XCD queue: 45 ranks x 4 streams
#define NSPLITI 416             // split items: qt 19..31 x 32 streams
#define PSLOT   4224            // floats per partial slot: 64x64 O + 64 m + 64 l
#define SC_  0.18033688f        // 0.125 * log2(e)  (QK scale, log2 domain)
#define TH_  170.238f           // 118 * log2(e)    (exact-underflow cutoff)

typedef __attribute__((ext_vector_type(8))) short short8;
typedef __attribute__((ext_vector_type(4))) float f32x4;

__device__ __forceinline__ float __exp2(float x) { return __builtin_amdgcn_exp2f(x); }

// async global->LDS, 16B per lane, dest = wave-uniform base + lane*16
__device__ __forceinline__ void gll16(const __hip_bfloat16* g, __hip_bfloat16* l) {
    __builtin_amdgcn_global_load_lds(
        (const __attribute__((address_space(1))) void*)g,
        (__attribute__((address_space(3))) void*)l, 16, 0, 0);
}

// R14 unit order table (LPT within each stream): code = (qt<<2)|part,
// part: 0=lower half (mem + kt 0..mid-1), 1=upper half (kt mid..qt),
// 2=unsplit (qt<=18). Sorted descending by tile count (max 20 = unsplit qt18).
__device__ const unsigned char UORD[45] = {
    74, 70, 66, 124, 62, 125, 120, 121, 116, 58,
    117, 112, 113, 108, 54, 109, 104, 105, 100, 50,
    101, 96, 97, 92, 46, 93, 88, 89, 84, 42,
    85, 80, 81, 76, 38, 77, 34, 30, 26, 22,
    18, 14, 10, 6, 2
};

// ---------------------------------------------------------------------------
// prep: fused prologue (independent parts, branch on block range).
//   blocks [0,2048):    inputs fp32 -> bf16 Ax
//   blocks [2048,3072): weights fp32 -> transposed bf16 Wt[g*1024+n][k]
//   blocks [3072,3104): last-row K in fp32 (retrieval stays exact)
//   block 0, tid<8:     zero the 8 per-XCD work-steal counters
// ---------------------------------------------------------------------------
__global__ __launch_bounds__(256) void prep(const float* __restrict__ inputs,
                                            const float* __restrict__ Wq,
                                            const float* __restrict__ Wk,
                                            const float* __restrict__ Wv,
                                            const float* __restrict__ Wo,
                                            __hip_bfloat16* __restrict__ Ax,
                                            __hip_bfloat16* __restrict__ Wt,
                                            float* __restrict__ lk,
                                            int* __restrict__ ctr) {
    const int bx = blockIdx.x, tid = threadIdx.x;
    if (bx == 0 && tid < 8) ctr[tid] = 0;

    if (bx < 2048) {
        const size_t i = ((size_t)bx * 256 + tid) * 8;
        float4 a = *(const float4*)&inputs[i];
        float4 b = *(const float4*)&inputs[i + 4];
        alignas(16) __hip_bfloat16 t[8];
        t[0] = __float2bfloat16(a.x); t[1] = __float2bfloat16(a.y);
        t[2] = __float2bfloat16(a.z); t[3] = __float2bfloat16(a.w);
        t[4] = __float2bfloat16(b.x); t[5] = __float2bfloat16(b.y);
        t[6] = __float2bfloat16(b.z); t[7] = __float2bfloat16(b.w);
        *(short8*)&Ax[i] = *(short8*)t;
        return;
    }
    if (bx < 3072) {
        const int idx = bx - 2048;
        const int g = idx >> 8, rem = idx & 255;
        const float* W = (g == 0) ? Wq : (g == 1) ? Wk : (g == 2) ? Wv : Wo;
        const int n0 = (rem & 15) * 64, k0 = (rem >> 4) * 64;
        __shared__ float T[64][65];
        {
            const int r = tid >> 4, c4 = (tid & 15) * 4;
#pragma unroll
            for (int p = 0; p < 4; ++p) {
                float4 v = *(const float4*)&W[(size_t)(k0 + r + p * 16) * 1024 + n0 + c4];
                T[r + p * 16][c4 + 0] = v.x; T[r + p * 16][c4 + 1] = v.y;
                T[r + p * 16][c4 + 2] = v.z; T[r + p * 16][c4 + 3] = v.w;
            }
        }
        __syncthreads();
        {
            const int n = tid >> 3, off = (tid & 7) * 8;
#pragma unroll
            for (int p = 0; p < 2; ++p) {
                const int nn = n + p * 32;
                alignas(16) __hip_bfloat16 t[8];
#pragma unroll
                for (int j = 0; j < 8; ++j) t[j] = __float2bfloat16(T[off + j][nn]);
                *(short8*)&Wt[((size_t)(g * 1024 + n0 + nn)) * 1024 + k0 + off] = *(short8*)t;
            }
        }
        return;
    }
    {   // lastk: lk[b,:] = inputs[b, S-1, :] @ Wk (fp32)
        const int idx = bx - 3072;
        const int xblk = idx & 15, b = idx >> 4;
        const int cl = tid & 63;
        const int col = xblk * 64 + cl;
        const int kq = tid >> 6;
        __shared__ float xr[1024];
        __shared__ float part[4][64];
        for (int i = tid; i < 1024; i += 256)
            xr[i] = inputs[((size_t)(b * S_ + S_ - 1)) * 1024 + i];
        __syncthreads();
        float acc = 0.f;
#pragma unroll 4
        for (int k = kq * 256; k < kq * 256 + 256; ++k)
            acc += xr[k] * Wk[(size_t)k * 1024 + col];
        part[kq][cl] = acc;
        __syncthreads();
        if (tid < 64)
            lk[b * 1024 + xblk * 64 + tid] =
                part[0][tid] + part[1][tid] + part[2][tid] + part[3][tid];
    }
}

// ---------------------------------------------------------------------------
// bf16 MFMA GEMM, m97 structure (R9 exact — swizzle experiment reverted).
// ---------------------------------------------------------------------------
__device__ __forceinline__ void store_out(__hip_bfloat16* p, float x) { *p = __float2bfloat16(x); }
__device__ __forceinline__ void store_out(float* p, float x) { *p = x; }

template <typename OutT>
__global__ __launch_bounds__(256) void gemm_mfma(const __hip_bfloat16* __restrict__ A,
                                                 const __hip_bfloat16* __restrict__ Bt,
                                                 OutT* __restrict__ C, int ldc) {
    __shared__ __hip_bfloat16 As[128 * 32];
    __shared__ __hip_bfloat16 Bs[128 * 32];
    const int tid = threadIdx.x;
    const int wave = tid >> 6, lane = tid & 63;
    const int quad = lane >> 4, lm = lane & 15;
    const int wr = wave >> 1, wc = wave & 1;
    const int m0 = blockIdx.y * 128, n0 = blockIdx.x * 128;

    const int r0 = tid >> 2, c0 = (tid & 3) * 8;
    const __hip_bfloat16* ga0 = &A[(size_t)(m0 + r0) * 1024 + c0];
    const __hip_bfloat16* ga1 = &A[(size_t)(m0 + 64 + r0) * 1024 + c0];
    const __hip_bfloat16* gb0 = &Bt[(size_t)(n0 + r0) * 1024 + c0];
    const __hip_bfloat16* gb1 = &Bt[(size_t)(n0 + 64 + r0) * 1024 + c0];
    __hip_bfloat16* la0 = &As[(wave * 64) * 8];
    __hip_bfloat16* la1 = &As[(256 + wave * 64) * 8];
    __hip_bfloat16* lb0 = &Bs[(wave * 64) * 8];
    __hip_bfloat16* lb1 = &Bs[(256 + wave * 64) * 8];

    f32x4 acc[4][4];
#pragma unroll
    for (int i = 0; i < 4; ++i)
#pragma unroll
        for (int j = 0; j < 4; ++j) acc[i][j] = (f32x4){0.f, 0.f, 0.f, 0.f};

    for (int k0 = 0; k0 < 1024; k0 += 32) {
        __syncthreads();
        gll16(ga0 + k0, la0);
        gll16(ga1 + k0, la1);
        gll16(gb0 + k0, lb0);
        gll16(gb1 + k0, lb1);
        __syncthreads();
        short8 af[4], bf4[4];
#pragma unroll
        for (int mt = 0; mt < 4; ++mt)
            af[mt] = *(const short8*)&As[(wr * 64 + mt * 16 + lm) * 32 + quad * 8];
#pragma unroll
        for (int nt = 0; nt < 4; ++nt)
            bf4[nt] = *(const short8*)&Bs[(wc * 64 + nt * 16 + lm) * 32 + quad * 8];
#pragma unroll
        for (int mt = 0; mt < 4; ++mt)
#pragma unroll
            for (int nt = 0; nt < 4; ++nt)
                acc[mt][nt] = __builtin_amdgcn_mfma_f32_16x16x32_bf16(
                    af[mt], bf4[nt], acc[mt][nt], 0, 0, 0);
    }
#pragma unroll
    for (int mt = 0; mt < 4; ++mt)
#pragma unroll
        for (int nt = 0; nt < 4; ++nt) {
            const int col = n0 + wc * 64 + nt * 16 + lm;
#pragma unroll
            for (int i = 0; i < 4; ++i) {
                const int row = m0 + wr * 64 + mt * 16 + quad * 4 + i;
                store_out(&C[(size_t)row * ldc + col], acc[mt][nt][i]);
            }
        }
}

// ---------------------------------------------------------------------------
// 64x128-tile variant for the out-projection GEMM (R9 exact, proven win).
// ---------------------------------------------------------------------------
template <typename OutT>
__global__ __launch_bounds__(256) void gemm_mfma64(const __hip_bfloat16* __restrict__ A,
                                                   const __hip_bfloat16* __restrict__ Bt,
                                                   OutT* __restrict__ C, int ldc) {
    __shared__ __hip_bfloat16 As[64 * 32];
    __shared__ __hip_bfloat16 Bs[128 * 32];
    const int tid = threadIdx.x;
    const int wave = tid >> 6, lane = tid & 63;
    const int quad = lane >> 4, lm = lane & 15;
    const int wr = wave >> 1, wc = wave & 1;
    const int m0 = blockIdx.y * 64, n0 = blockIdx.x * 128;

    const int r0 = tid >> 2, c0 = (tid & 3) * 8;
    const __hip_bfloat16* ga  = &A[(size_t)(m0 + r0) * 1024 + c0];
    const __hip_bfloat16* gb0 = &Bt[(size_t)(n0 + r0) * 1024 + c0];
    const __hip_bfloat16* gb1 = &Bt[(size_t)(n0 + 64 + r0) * 1024 + c0];
    __hip_bfloat16* la  = &As[(wave * 64) * 8];
    __hip_bfloat16* lb0 = &Bs[(wave * 64) * 8];
    __hip_bfloat16* lb1 = &Bs[(256 + wave * 64) * 8];

    f32x4 acc[2][4];
#pragma unroll
    for (int i = 0; i < 2; ++i)
#pragma unroll
        for (int j = 0; j < 4; ++j) acc[i][j] = (f32x4){0.f, 0.f, 0.f, 0.f};

    for (int k0 = 0; k0 < 1024; k0 += 32) {
        __syncthreads();
        gll16(ga + k0, la);
        gll16(gb0 + k0, lb0);
        gll16(gb1 + k0, lb1);
        __syncthreads();
        short8 af[2], bf4[4];
#pragma unroll
        for (int mt = 0; mt < 2; ++mt)
            af[mt] = *(const short8*)&As[(wr * 32 + mt * 16 + lm) * 32 + quad * 8];
#pragma unroll
        for (int nt = 0; nt < 4; ++nt)
            bf4[nt] = *(const short8*)&Bs[(wc * 64 + nt * 16 + lm) * 32 + quad * 8];
#pragma unroll
        for (int mt = 0; mt < 2; ++mt)
#pragma unroll
            for (int nt = 0; nt < 4; ++nt)
                acc[mt][nt] = __builtin_amdgcn_mfma_f32_16x16x32_bf16(
                    af[mt], bf4[nt], acc[mt][nt], 0, 0, 0);
    }
#pragma unroll
    for (int mt = 0; mt < 2; ++mt)
#pragma unroll
        for (int nt = 0; nt < 4; ++nt) {
            const int col = n0 + wc * 64 + nt * 16 + lm;
#pragma unroll
            for (int i = 0; i < 4; ++i) {
                const int row = m0 + wr * 32 + mt * 16 + quad * 4 + i;
                store_out(&C[(size_t)row * ldc + col], acc[mt][nt][i]);
            }
        }
}

// ---------------------------------------------------------------------------
// sims + topk (unchanged).
// ---------------------------------------------------------------------------
__global__ __launch_bounds__(256) void sims_kernel(const float* __restrict__ lk,
                                                   const float* __restrict__ events,
                                                   float* __restrict__ sims) {
    const int b = blockIdx.y;
    const int tid = threadIdx.x;
    const int wave = tid >> 6, lane = tid & 63;
    __shared__ float qv[1024];
    for (int i = tid; i < 1024; i += 256)
        qv[i] = lk[b * 1024 + i];
    __syncthreads();

    const int m = blockIdx.x * 4 + wave;
    if (m >= MEM_) return;
    const float* ev = &events[(size_t)m * 1024];
    float dot = 0.f, nrm = 0.f;
    for (int d = lane; d < 1024; d += 64) {
        float e = ev[d];
        dot += qv[d] * e;
        nrm += e * e;
    }
    for (int off = 32; off; off >>= 1) {
        dot += __shfl_down(dot, off);
        nrm += __shfl_down(nrm, off);
    }
    if (lane == 0) sims[b * 1024 + m] = dot / (sqrtf(nrm) + 1e-8f);
}

__global__ __launch_bounds__(64) void topk10_kernel(const float* __restrict__ sims,
                                                    int* __restrict__ topk) {
    const int b = blockIdx.x;
    const int lane = threadIdx.x;
    const int base = lane * 16;
    float v[16];
#pragma unroll
    for (int j = 0; j < 16; ++j) {
        const int m = base + j;
        v[j] = (m < MEM_) ? sims[b * 1024 + m] : -INFINITY;
    }
    for (int it = 0; it < KTOT; ++it) {
        float best = -INFINITY; int bi = 0x7fffffff;
#pragma unroll
        for (int j = 0; j < 16; ++j)
            if (v[j] > best) { best = v[j]; bi = base + j; }
        for (int off = 32; off; off >>= 1) {
            const float ob = __shfl_xor(best, off);
            const int   oi = __shfl_xor(bi, off);
            if (ob > best || (ob == best && oi < bi)) { best = ob; bi = oi; }
        }
        if (lane == 0) topk[b * KTOT + it] = bi;
#pragma unroll
        for (int j = 0; j < 16; ++j)
            if (base + j == bi) v[j] = -INFINITY;
    }
}

// ---------------------------------------------------------------------------
// Flash attention R14 = R13 engine (XCD queues; FETCH 55->9.9 MB proven) +
// fence-free KV split WITHIN each queue.
// Post-mortem R13: FETCH collapsed but dur didn't -> L2-miss latency
// falsified; makespan = longest chain x stubborn ~2.27 us/tile (75/33).
// R12 showed chain 33->20 but conflated with locality loss (global queue,
// FETCH 84 MB -> 4.4 us/tile). Here both halves of a split item stay in
// the SAME queue -> same XCD L2 -> locality preserved while chain drops
// 33 -> 20 tiles (longest = unsplit qt=18).
//  * split items qt>=19: lower = mem + kt 0..mid-1, upper = kt mid..qt
//    (mid=(qt+1)>>1); each an independent unit with own online softmax.
//    Partials (unnorm O f32 + per-row m,l) -> plain stores into the dead
//    [0,14.05MB) ws region (Wo-T at +14.29MB untouched). NO fences/atomics
//    (R10's threadfence disaster avoided); separate merge kernel after.
//  * per-queue LPT via UORD table: 45 ranks x 4 streams = 180 units/queue.
//  * grid 1024 (4 blocks/CU): first 128 units/queue start at t0 (all long
//    units); remaining 52 are the shortest, absorbed by finishing blocks.
// Kept verbatim: single-buffer LDS, 2 barriers/tile, reg prefetch,
// ones-column l-accum, frozen-max cutoff (per-half exact), Q-in-regs,
// log2-domain softmax, zero-once Vt.
// ---------------------------------------------------------------------------
__global__ __launch_bounds__(256) void attn_mfma(
        const __hip_bfloat16* __restrict__ qkv,
        const float* __restrict__ events,
        const int* __restrict__ topk,
        const float* __restrict__ amask,
        __hip_bfloat16* __restrict__ out,
        int* __restrict__ ctr,
        float* __restrict__ partb) {
    const int tid = threadIdx.x;
    const int wave = tid >> 6, lane = tid & 63;
    const int quad = lane >> 4, lm = lane & 15;
    const int g = blockIdx.x & 7;      // XCD queue id (round-robin heuristic)

    const __hip_bfloat16* qf = qkv;
    const __hip_bfloat16* kf = qkv + 1024;
    const __hip_bfloat16* vf = qkv + 2048;

    __shared__ __hip_bfloat16 Ks[64 * LDK];
    __shared__ __hip_bfloat16 Vt[80 * LDK];   // [d][kcol]; rows 64..79 static (64=ones)
    __shared__ __hip_bfloat16 Ps[64 * LDK];
    __shared__ float colb[64];
    __shared__ float redb[4];
    __shared__ int sItem;

    const int va = tid & 31, vdc = tid >> 5;
    const int vtok0 = va * 2, vd0 = vdc * 8;

    // one-time init: finite Vt fill (stale x P==0 = 0 needs finite, not NaN)
    // and the static ones/zero rows.
    for (int i = tid * 8; i < 64 * LDK; i += 256 * 8)
        *(int4*)&Vt[i] = make_int4(0, 0, 0, 0);
    for (int i = tid; i < 16 * LDK; i += 256) {
        const int r = i / LDK;
        Vt[64 * LDK + i] = __float2bfloat16(r == 0 ? 1.0f : 0.0f);
    }

    for (;;) {
        __syncthreads();    // prev unit's LDS readers done; also covers Vt init
        if (tid == 0) sItem = atomicAdd(&ctr[g], 1);
        __syncthreads();
        const int n = sItem;
        if (n >= QITEMS) break;

        // ---- unit decode: rank in UORD (LPT), stream = g*4 + (n&3) ----
        const int entry = UORD[n >> 2];
        const int qt = entry >> 2, part = entry & 3;
        const int s = g * 4 + (n & 3);
        const int h = 15 - (s >> 1);
        const int b = s & 1;
        const bool split = (part < 2);
        const int mid = (qt + 1) >> 1;
        const int kstart = (part == 1) ? mid : 0;
        const int kend   = (part == 0) ? (mid - 1) : qt;
        const bool haveMem = (part != 1);
        const int sidx = (31 - qt) * 32 + s;   // only meaningful when split
        const int q0 = qt * 64;
        const float slope2 = __exp2(-0.5f * (float)(h + 1)) * 1.44269504f;  // log2 dom

        short8 pk[2], pv0, pv1;
        float pam = 1.f;
        auto prefetchKV = [&](int kt) {
            const __hip_bfloat16* ks = &kf[((size_t)(b * S_ + kt * 64)) * 3072 + h * 64];
#pragma unroll
            for (int u = 0; u < 2; ++u) {
                int c = tid * 2 + u, row = c >> 3, off = (c & 7) * 8;
                pk[u] = *(const short8*)&ks[(size_t)row * 3072 + off];
            }
            const __hip_bfloat16* v0 =
                &vf[((size_t)(b * S_ + kt * 64 + vtok0)) * 3072 + h * 64 + vd0];
            pv0 = *(const short8*)v0;
            pv1 = *(const short8*)(v0 + 3072);
            if (tid < 64) pam = amask[b * S_ + kt * 64 + tid];
        };
        auto stageKV = [&](int kt) {
#pragma unroll
            for (int u = 0; u < 2; ++u) {
                int c = tid * 2 + u, row = c >> 3, off = (c & 7) * 8;
                *(short8*)&Ks[row * LDK + off] = pk[u];
            }
#pragma unroll
            for (int j = 0; j < 8; ++j) {
                short2 pr; pr.x = pv0[j]; pr.y = pv1[j];
                *(short2*)&Vt[(vd0 + j) * LDK + vtok0] = pr;
            }
            if (tid < 64)
                colb[tid] = fmaf(-slope2, (float)(kt * 64 + tid), (1.f - pam) * NEG9);
        };

        prefetchKV(kstart);     // earliest possible issue

        // ---- Q fragments straight into registers ----
        short8 qa[2];
        {
            const __hip_bfloat16* qsrc =
                &qf[((size_t)(b * S_ + q0 + wave * 16 + lm)) * 3072 + h * 64 + quad * 8];
            qa[0] = *(const short8*)qsrc;
            qa[1] = *(const short8*)(qsrc + 32);
        }
        // memory tile (K rows 0..9; Vt cols 0..9; stale rest exactly masked:
        // Ks via cc>=KTOT -> NEG9, Vt via Ps == 0.0 exactly)
        if (haveMem && tid < 80) {
            const int tok = tid >> 3, d0 = (tid & 7) * 8;
            const int ev = topk[b * KTOT + tok];
            const float* es = &events[(size_t)ev * 1024 + h * 64 + d0];
#pragma unroll
            for (int j = 0; j < 8; ++j) {
                __hip_bfloat16 x = __float2bfloat16(es[j]);
                Ks[tok * LDK + d0 + j] = x;
                Vt[(d0 + j) * LDK + tok] = x;
            }
        }

        float m_[4], mshift[4];
        f32x4 Oa[5];        // Oa[4] = softmax denominator column
#pragma unroll
        for (int i = 0; i < 4; ++i) {
            m_[i] = -INFINITY;
            mshift[i] = -slope2 * (float)(q0 + wave * 16 + quad * 4 + i);
        }
#pragma unroll
        for (int nt = 0; nt < 5; ++nt) Oa[nt] = (f32x4){0.f, 0.f, 0.f, 0.f};

        auto qk = [&](f32x4* sa) {
#pragma unroll
            for (int nt = 0; nt < 4; ++nt) sa[nt] = (f32x4){0.f, 0.f, 0.f, 0.f};
#pragma unroll
            for (int ks2 = 0; ks2 < 2; ++ks2) {
#pragma unroll
                for (int nt = 0; nt < 4; ++nt) {
                    short8 bk = *(const short8*)&Ks[(nt * 16 + lm) * LDK + ks2 * 32 + quad * 8];
                    sa[nt] = __builtin_amdgcn_mfma_f32_16x16x32_bf16(qa[ks2], bk, sa[nt], 0, 0, 0);
                }
            }
        };
        auto pv = [&]() {
#pragma unroll
            for (int ks2 = 0; ks2 < 2; ++ks2) {
                short8 ap = *(const short8*)&Ps[(wave * 16 + lm) * LDK + ks2 * 32 + quad * 8];
#pragma unroll
                for (int nt = 0; nt < 5; ++nt) {   // nt=4: ones column -> l
                    short8 bv = *(const short8*)&Vt[(nt * 16 + lm) * LDK + ks2 * 32 + quad * 8];
                    Oa[nt] = __builtin_amdgcn_mfma_f32_16x16x32_bf16(ap, bv, Oa[nt], 0, 0, 0);
                }
            }
        };

        auto softmax_online = [&](const f32x4* sa, int kt, bool diag) {
            float cb[4];
            if (kt >= 0) {
#pragma unroll
                for (int nt = 0; nt < 4; ++nt) cb[nt] = colb[nt * 16 + lm];
            }
#pragma unroll
            for (int i = 0; i < 4; ++i) {
                const int lr = wave * 16 + quad * 4 + i;
                const int rg = q0 + lr;
                float s2[4];
#pragma unroll
                for (int nt = 0; nt < 4; ++nt) {
                    const int cc = nt * 16 + lm;
                    if (kt < 0) {
                        s2[nt] = (cc < KTOT) ? fmaf(sa[nt][i], SC_, mshift[i]) : NEG9;
                    } else {
                        float v = fmaf(sa[nt][i], SC_, cb[nt]);
                        s2[nt] = (diag && kt * 64 + cc > rg) ? NEG9 : v;
                    }
                }
                float rmax = fmaxf(fmaxf(s2[0], s2[1]), fmaxf(s2[2], s2[3]));
#pragma unroll
                for (int off = 1; off < 16; off <<= 1)
                    rmax = fmaxf(rmax, __shfl_xor(rmax, off, 16));
                const float newm = fmaxf(m_[i], rmax);
                const float al = __exp2(m_[i] - newm);
                m_[i] = newm;
#pragma unroll
                for (int nt = 0; nt < 4; ++nt)
                    Ps[lr * LDK + nt * 16 + lm] = __float2bfloat16(__exp2(s2[nt] - newm));
#pragma unroll
                for (int nt = 0; nt < 5; ++nt)     // includes l-column
                    Oa[nt][i] *= al;
            }
        };

        auto softmax_fast = [&](const f32x4* sa, int cbase, bool diag) {
            float cb[4];
#pragma unroll
            for (int nt = 0; nt < 4; ++nt) cb[nt] = colb[nt * 16 + lm];
#pragma unroll
            for (int i = 0; i < 4; ++i) {
                const int lr = wave * 16 + quad * 4 + i;
                const float cm = m_[i];
                float p[4];
#pragma unroll
                for (int nt = 0; nt < 4; ++nt)
                    p[nt] = __exp2(fmaf(sa[nt][i], SC_, cb[nt]) - cm);
                if (diag) {
                    const int rg = q0 + lr;
#pragma unroll
                    for (int nt = 0; nt < 4; ++nt)
                        if (cbase + nt * 16 + lm > rg) p[nt] = 0.f;
                }
#pragma unroll
                for (int nt = 0; nt < 4; ++nt)
                    Ps[lr * LDK + nt * 16 + lm] = __float2bfloat16(p[nt]);
            }
        };

        // ---- memory tile (online; lower/unsplit units only) ----
        if (haveMem) {
            __syncthreads();        // publish mem tile
            f32x4 sa[4];
            qk(sa);
            softmax_online(sa, -1, false);
            pv();
            __syncthreads();        // mem readers done before stage overwrites
        }
        // ---- first regular tile kt = kstart (online) ----
        stageKV(kstart);
        if (kstart < kend) prefetchKV(kstart + 1);
        __syncthreads();
        {
            f32x4 sa[4];
            qk(sa);
            softmax_online(sa, kstart, kstart == qt);
            pv();
        }

        // ---- freeze max; block-min(m) -> exact-underflow cutoff ----
        int kend2 = kstart;
        if (kend > kstart) {
            float mloc = fminf(fminf(m_[0], m_[1]), fminf(m_[2], m_[3]));
#pragma unroll
            for (int off = 1; off < 64; off <<= 1)
                mloc = fminf(mloc, __shfl_xor(mloc, off, 64));
            if (lane == 0) redb[wave] = mloc;
            __syncthreads();        // redb visible + first-tile readers done
            const float mmin = fminf(fminf(redb[0], redb[1]), fminf(redb[2], redb[3]));
            kend2 = min(kend, (int)((TH_ - mmin) / (64.f * slope2)));
        }
        for (int kt = kstart + 1; kt <= kend2; ++kt) {
            __syncthreads();
            stageKV(kt);
            if (kt < kend2) prefetchKV(kt + 1);
            __syncthreads();
            f32x4 sa[4];
            qk(sa);
            softmax_fast(sa, kt * 64, kt == qt);
            pv();
        }

        // ---- epilogue ----
        float l_[4];
#pragma unroll
        for (int i = 0; i < 4; ++i) l_[i] = __shfl(Oa[4][i], (lane & 48));
        if (!split) {
#pragma unroll
            for (int i = 0; i < 4; ++i) {
                const int lr = wave * 16 + quad * 4 + i;
                const float inv = 1.f / l_[i];
                __hip_bfloat16* dst = &out[((size_t)(b * S_ + q0 + lr)) * 1024 + h * 64 + lm];
#pragma unroll
                for (int nt = 0; nt < 4; ++nt)
                    dst[nt * 16] = __float2bfloat16(Oa[nt][i] * inv);
            }
        } else {
            // plain partial dump; merge happens in a later kernel (no fence)
            float* psl = partb + (size_t)(sidx * 2 + part) * PSLOT;
#pragma unroll
            for (int i = 0; i < 4; ++i) {
                const int lr = wave * 16 + quad * 4 + i;
#pragma unroll
                for (int nt = 0; nt < 4; ++nt)
                    psl[lr * 64 + nt * 16 + lm] = Oa[nt][i];
                if (lm == 0) {
                    psl[4096 + lr] = m_[i];
                    psl[4160 + lr] = l_[i];
                }
            }
        }
    }
}

// ---------------------------------------------------------------------------
// merge_split: combine the two halves of each split item (flash merge).
// One block per split item; memory-bound; runs after attn (kernel boundary
// provides ordering, no fences needed).
// ---------------------------------------------------------------------------
__global__ __launch_bounds__(256) void merge_split(const float* __restrict__ partb,
                                                   __hip_bfloat16* __restrict__ out) {
    const int sidx = blockIdx.x;           // 0..NSPLITI-1 -> qt 31..19
    const int qt = 31 - (sidx >> 5);
    const int s = sidx & 31;
    const int h = 15 - (s >> 1);
    const int b = s & 1;
    const int q0 = qt * 64;
    const float* pA = partb + (size_t)(sidx * 2) * PSLOT;
    const float* pB = pA + PSLOT;
    const int t = threadIdx.x;
    const int row = t >> 2, c0 = (t & 3) * 16;

    const float mA = pA[4096 + row], lA = pA[4160 + row];
    const float mB = pB[4096 + row], lB = pB[4160 + row];
    const float mm = fmaxf(mA, mB);
    const float fA = __exp2(mA - mm), fB = __exp2(mB - mm);
    const float inv = 1.f / (lA * fA + lB * fB);
    const float wA = fA * inv, wB = fB * inv;

    __hip_bfloat16* dst = &out[((size_t)(b * S_ + q0 + row)) * 1024 + h * 64 + c0];
    alignas(16) __hip_bfloat16 tmp[16];
#pragma unroll
    for (int j = 0; j < 16; j += 4) {
        f32x4 a = *(const f32x4*)&pA[row * 64 + c0 + j];
        f32x4 v = *(const f32x4*)&pB[row * 64 + c0 + j];
#pragma unroll
        for (int e = 0; e < 4; ++e)
            tmp[j + e] = __float2bfloat16(a[e] * wA + v[e] * wB);
    }
    *(short8*)&dst[0] = *(short8*)&tmp[0];
    *(short8*)&dst[8] = *(short8*)&tmp[8];
}

// ---------------------------------------------------------------------------
extern "C" void kernel_launch(void* const* d_in, const int* in_sizes, int n_in,
                              void* d_out, int out_size, void* d_ws, size_t ws_size,
                              hipStream_t stream) {
    const float* inputs = (const float*)d_in[0];
    const float* amask  = (const float*)d_in[1];
    const float* Wq     = (const float*)d_in[2];
    const float* Wk     = (const float*)d_in[3];
    const float* Wv     = (const float*)d_in[4];
    const float* Wo     = (const float*)d_in[5];
    const float* events = (const float*)d_in[6];
    float* out = (float*)d_out;

    // ws: Ax 8MB | Wt 8MB | qkv 24MB | ao 8MB | lk | sims | topk | ctr[8]
    // During attn, [0 .. 14.29MB) is dead (Ax + Wq/Wk/Wv-transposed; gemm1
    // done, gemm2 only needs Wo-T at +14.29MB). The 832 partial slots
    // (14.05MB) live there; merge runs between attn and gemm2.
    __hip_bfloat16* Ax  = (__hip_bfloat16*)d_ws;
    __hip_bfloat16* Wt  = Ax + (size_t)NROW * 1024;
    __hip_bfloat16* qkv = Wt + (size_t)4096 * 1024;
    __hip_bfloat16* ao  = qkv + (size_t)NROW * 3072;
    float* lk   = (float*)(ao + (size_t)NROW * 1024);
    float* sims = lk + 2 * 1024;
    int* topk   = (int*)(sims + 2 * 1024);
    int* ctr    = topk + B_ * KTOT;
    float* partb = (float*)d_ws;    // aliases Ax + first 6MB of Wt (dead)

    dim3 blk(256);
    prep<<<3104, blk, 0, stream>>>(inputs, Wq, Wk, Wv, Wo, Ax, Wt, lk, ctr);
    sims_kernel<<<dim3(250, B_), blk, 0, stream>>>(lk, events, sims);
    topk10_kernel<<<B_, 64, 0, stream>>>(sims, topk);
    gemm_mfma<__hip_bfloat16><<<dim3(24, 32), blk, 0, stream>>>(Ax, Wt, qkv, 3072);
    attn_mfma<<<1024, blk, 0, stream>>>(qkv, events, topk, amask, ao, ctr, partb);
    merge_split<<<NSPLITI, blk, 0, stream>>>(partb, ao);
    gemm_mfma64<float><<<dim3(8, 64), blk, 0, stream>>>(
        ao, Wt + (size_t)3072 * 1024, out, 1024);
}

// Round 8
// 235.048 us; speedup vs baseline: 1.1042x; 1.1042x over previous
//
#include <hip/hip_runtime.h>
#include <hip/hip_bf16.h>
#include <math.h>

// Problem constants
#define B_   2
#define S_   2048
#define DM_  1024
#define H_   16
#define HD_  64
#define MEM_ 1000
#define KTOT 10
#define NROW (B_ * S_)          // 4096
#define NEG9 (-1e9f)
#define LDK  72                 // bf16 row stride in attention LDS tiles
#define QITEMS 128              // items per XCD queue: 32 qt x 4 streams
#define SC_  0.18033688f        // 0.125 * log2(e)  (QK scale, log2 domain)
#define TH_  170.238f           // 118 * log2(e)    (exact-underflow cutoff)

typedef __attribute__((ext_vector_type(8))) short short8;
typedef __attribute__((ext_vector_type(4))) float f32x4;

__device__ __forceinline__ float __exp2(float x) { return __builtin_amdgcn_exp2f(x); }

// async global->LDS, 16B per lane, dest = wave-uniform base + lane*16
__device__ __forceinline__ void gll16(const __hip_bfloat16* g, __hip_bfloat16* l) {
    __builtin_amdgcn_global_load_lds(
        (const __attribute__((address_space(1))) void*)g,
        (__attribute__((address_space(3))) void*)l, 16, 0, 0);
}

// ---------------------------------------------------------------------------
// prep: fused prologue (independent parts, branch on block range).
//   blocks [0,2048):    inputs fp32 -> bf16 Ax
//   blocks [2048,3072): weights fp32 -> transposed bf16 Wt[g*1024+n][k]
//   blocks [3072,3104): last-row K in fp32 (retrieval stays exact)
//   block 0, tid<8:     zero the 8 per-XCD work-steal counters
// ---------------------------------------------------------------------------
__global__ __launch_bounds__(256) void prep(const float* __restrict__ inputs,
                                            const float* __restrict__ Wq,
                                            const float* __restrict__ Wk,
                                            const float* __restrict__ Wv,
                                            const float* __restrict__ Wo,
                                            __hip_bfloat16* __restrict__ Ax,
                                            __hip_bfloat16* __restrict__ Wt,
                                            float* __restrict__ lk,
                                            int* __restrict__ ctr) {
    const int bx = blockIdx.x, tid = threadIdx.x;
    if (bx == 0 && tid < 8) ctr[tid] = 0;

    if (bx < 2048) {
        const size_t i = ((size_t)bx * 256 + tid) * 8;
        float4 a = *(const float4*)&inputs[i];
        float4 b = *(const float4*)&inputs[i + 4];
        alignas(16) __hip_bfloat16 t[8];
        t[0] = __float2bfloat16(a.x); t[1] = __float2bfloat16(a.y);
        t[2] = __float2bfloat16(a.z); t[3] = __float2bfloat16(a.w);
        t[4] = __float2bfloat16(b.x); t[5] = __float2bfloat16(b.y);
        t[6] = __float2bfloat16(b.z); t[7] = __float2bfloat16(b.w);
        *(short8*)&Ax[i] = *(short8*)t;
        return;
    }
    if (bx < 3072) {
        const int idx = bx - 2048;
        const int g = idx >> 8, rem = idx & 255;
        const float* W = (g == 0) ? Wq : (g == 1) ? Wk : (g == 2) ? Wv : Wo;
        const int n0 = (rem & 15) * 64, k0 = (rem >> 4) * 64;
        __shared__ float T[64][65];
        {
            const int r = tid >> 4, c4 = (tid & 15) * 4;
#pragma unroll
            for (int p = 0; p < 4; ++p) {
                float4 v = *(const float4*)&W[(size_t)(k0 + r + p * 16) * 1024 + n0 + c4];
                T[r + p * 16][c4 + 0] = v.x; T[r + p * 16][c4 + 1] = v.y;
                T[r + p * 16][c4 + 2] = v.z; T[r + p * 16][c4 + 3] = v.w;
            }
        }
        __syncthreads();
        {
            const int n = tid >> 3, off = (tid & 7) * 8;
#pragma unroll
            for (int p = 0; p < 2; ++p) {
                const int nn = n + p * 32;
                alignas(16) __hip_bfloat16 t[8];
#pragma unroll
                for (int j = 0; j < 8; ++j) t[j] = __float2bfloat16(T[off + j][nn]);
                *(short8*)&Wt[((size_t)(g * 1024 + n0 + nn)) * 1024 + k0 + off] = *(short8*)t;
            }
        }
        return;
    }
    {   // lastk: lk[b,:] = inputs[b, S-1, :] @ Wk (fp32)
        const int idx = bx - 3072;
        const int xblk = idx & 15, b = idx >> 4;
        const int cl = tid & 63;
        const int col = xblk * 64 + cl;
        const int kq = tid >> 6;
        __shared__ float xr[1024];
        __shared__ float part[4][64];
        for (int i = tid; i < 1024; i += 256)
            xr[i] = inputs[((size_t)(b * S_ + S_ - 1)) * 1024 + i];
        __syncthreads();
        float acc = 0.f;
#pragma unroll 4
        for (int k = kq * 256; k < kq * 256 + 256; ++k)
            acc += xr[k] * Wk[(size_t)k * 1024 + col];
        part[kq][cl] = acc;
        __syncthreads();
        if (tid < 64)
            lk[b * 1024 + xblk * 64 + tid] =
                part[0][tid] + part[1][tid] + part[2][tid] + part[3][tid];
    }
}

// ---------------------------------------------------------------------------
// bf16 MFMA GEMM, m97 structure (R9 exact).
// ---------------------------------------------------------------------------
__device__ __forceinline__ void store_out(__hip_bfloat16* p, float x) { *p = __float2bfloat16(x); }
__device__ __forceinline__ void store_out(float* p, float x) { *p = x; }

template <typename OutT>
__global__ __launch_bounds__(256) void gemm_mfma(const __hip_bfloat16* __restrict__ A,
                                                 const __hip_bfloat16* __restrict__ Bt,
                                                 OutT* __restrict__ C, int ldc) {
    __shared__ __hip_bfloat16 As[128 * 32];
    __shared__ __hip_bfloat16 Bs[128 * 32];
    const int tid = threadIdx.x;
    const int wave = tid >> 6, lane = tid & 63;
    const int quad = lane >> 4, lm = lane & 15;
    const int wr = wave >> 1, wc = wave & 1;
    const int m0 = blockIdx.y * 128, n0 = blockIdx.x * 128;

    const int r0 = tid >> 2, c0 = (tid & 3) * 8;
    const __hip_bfloat16* ga0 = &A[(size_t)(m0 + r0) * 1024 + c0];
    const __hip_bfloat16* ga1 = &A[(size_t)(m0 + 64 + r0) * 1024 + c0];
    const __hip_bfloat16* gb0 = &Bt[(size_t)(n0 + r0) * 1024 + c0];
    const __hip_bfloat16* gb1 = &Bt[(size_t)(n0 + 64 + r0) * 1024 + c0];
    __hip_bfloat16* la0 = &As[(wave * 64) * 8];
    __hip_bfloat16* la1 = &As[(256 + wave * 64) * 8];
    __hip_bfloat16* lb0 = &Bs[(wave * 64) * 8];
    __hip_bfloat16* lb1 = &Bs[(256 + wave * 64) * 8];

    f32x4 acc[4][4];
#pragma unroll
    for (int i = 0; i < 4; ++i)
#pragma unroll
        for (int j = 0; j < 4; ++j) acc[i][j] = (f32x4){0.f, 0.f, 0.f, 0.f};

    for (int k0 = 0; k0 < 1024; k0 += 32) {
        __syncthreads();
        gll16(ga0 + k0, la0);
        gll16(ga1 + k0, la1);
        gll16(gb0 + k0, lb0);
        gll16(gb1 + k0, lb1);
        __syncthreads();
        short8 af[4], bf4[4];
#pragma unroll
        for (int mt = 0; mt < 4; ++mt)
            af[mt] = *(const short8*)&As[(wr * 64 + mt * 16 + lm) * 32 + quad * 8];
#pragma unroll
        for (int nt = 0; nt < 4; ++nt)
            bf4[nt] = *(const short8*)&Bs[(wc * 64 + nt * 16 + lm) * 32 + quad * 8];
#pragma unroll
        for (int mt = 0; mt < 4; ++mt)
#pragma unroll
            for (int nt = 0; nt < 4; ++nt)
                acc[mt][nt] = __builtin_amdgcn_mfma_f32_16x16x32_bf16(
                    af[mt], bf4[nt], acc[mt][nt], 0, 0, 0);
    }
#pragma unroll
    for (int mt = 0; mt < 4; ++mt)
#pragma unroll
        for (int nt = 0; nt < 4; ++nt) {
            const int col = n0 + wc * 64 + nt * 16 + lm;
#pragma unroll
            for (int i = 0; i < 4; ++i) {
                const int row = m0 + wr * 64 + mt * 16 + quad * 4 + i;
                store_out(&C[(size_t)row * ldc + col], acc[mt][nt][i]);
            }
        }
}

// ---------------------------------------------------------------------------
// 64x128-tile variant for the out-projection GEMM (R9 exact, proven win).
// ---------------------------------------------------------------------------
template <typename OutT>
__global__ __launch_bounds__(256) void gemm_mfma64(const __hip_bfloat16* __restrict__ A,
                                                   const __hip_bfloat16* __restrict__ Bt,
                                                   OutT* __restrict__ C, int ldc) {
    __shared__ __hip_bfloat16 As[64 * 32];
    __shared__ __hip_bfloat16 Bs[128 * 32];
    const int tid = threadIdx.x;
    const int wave = tid >> 6, lane = tid & 63;
    const int quad = lane >> 4, lm = lane & 15;
    const int wr = wave >> 1, wc = wave & 1;
    const int m0 = blockIdx.y * 64, n0 = blockIdx.x * 128;

    const int r0 = tid >> 2, c0 = (tid & 3) * 8;
    const __hip_bfloat16* ga  = &A[(size_t)(m0 + r0) * 1024 + c0];
    const __hip_bfloat16* gb0 = &Bt[(size_t)(n0 + r0) * 1024 + c0];
    const __hip_bfloat16* gb1 = &Bt[(size_t)(n0 + 64 + r0) * 1024 + c0];
    __hip_bfloat16* la  = &As[(wave * 64) * 8];
    __hip_bfloat16* lb0 = &Bs[(wave * 64) * 8];
    __hip_bfloat16* lb1 = &Bs[(256 + wave * 64) * 8];

    f32x4 acc[2][4];
#pragma unroll
    for (int i = 0; i < 2; ++i)
#pragma unroll
        for (int j = 0; j < 4; ++j) acc[i][j] = (f32x4){0.f, 0.f, 0.f, 0.f};

    for (int k0 = 0; k0 < 1024; k0 += 32) {
        __syncthreads();
        gll16(ga + k0, la);
        gll16(gb0 + k0, lb0);
        gll16(gb1 + k0, lb1);
        __syncthreads();
        short8 af[2], bf4[4];
#pragma unroll
        for (int mt = 0; mt < 2; ++mt)
            af[mt] = *(const short8*)&As[(wr * 32 + mt * 16 + lm) * 32 + quad * 8];
#pragma unroll
        for (int nt = 0; nt < 4; ++nt)
            bf4[nt] = *(const short8*)&Bs[(wc * 64 + nt * 16 + lm) * 32 + quad * 8];
#pragma unroll
        for (int mt = 0; mt < 2; ++mt)
#pragma unroll
            for (int nt = 0; nt < 4; ++nt)
                acc[mt][nt] = __builtin_amdgcn_mfma_f32_16x16x32_bf16(
                    af[mt], bf4[nt], acc[mt][nt], 0, 0, 0);
    }
#pragma unroll
    for (int mt = 0; mt < 2; ++mt)
#pragma unroll
        for (int nt = 0; nt < 4; ++nt) {
            const int col = n0 + wc * 64 + nt * 16 + lm;
#pragma unroll
            for (int i = 0; i < 4; ++i) {
                const int row = m0 + wr * 32 + mt * 16 + quad * 4 + i;
                store_out(&C[(size_t)row * ldc + col], acc[mt][nt][i]);
            }
        }
}

// ---------------------------------------------------------------------------
// sims + topk (unchanged).
// ---------------------------------------------------------------------------
__global__ __launch_bounds__(256) void sims_kernel(const float* __restrict__ lk,
                                                   const float* __restrict__ events,
                                                   float* __restrict__ sims) {
    const int b = blockIdx.y;
    const int tid = threadIdx.x;
    const int wave = tid >> 6, lane = tid & 63;
    __shared__ float qv[1024];
    for (int i = tid; i < 1024; i += 256)
        qv[i] = lk[b * 1024 + i];
    __syncthreads();

    const int m = blockIdx.x * 4 + wave;
    if (m >= MEM_) return;
    const float* ev = &events[(size_t)m * 1024];
    float dot = 0.f, nrm = 0.f;
    for (int d = lane; d < 1024; d += 64) {
        float e = ev[d];
        dot += qv[d] * e;
        nrm += e * e;
    }
    for (int off = 32; off; off >>= 1) {
        dot += __shfl_down(dot, off);
        nrm += __shfl_down(nrm, off);
    }
    if (lane == 0) sims[b * 1024 + m] = dot / (sqrtf(nrm) + 1e-8f);
}

__global__ __launch_bounds__(64) void topk10_kernel(const float* __restrict__ sims,
                                                    int* __restrict__ topk) {
    const int b = blockIdx.x;
    const int lane = threadIdx.x;
    const int base = lane * 16;
    float v[16];
#pragma unroll
    for (int j = 0; j < 16; ++j) {
        const int m = base + j;
        v[j] = (m < MEM_) ? sims[b * 1024 + m] : -INFINITY;
    }
    for (int it = 0; it < KTOT; ++it) {
        float best = -INFINITY; int bi = 0x7fffffff;
#pragma unroll
        for (int j = 0; j < 16; ++j)
            if (v[j] > best) { best = v[j]; bi = base + j; }
        for (int off = 32; off; off >>= 1) {
            const float ob = __shfl_xor(best, off);
            const int   oi = __shfl_xor(bi, off);
            if (ob > best || (ob == best && oi < bi)) { best = ob; bi = oi; }
        }
        if (lane == 0) topk[b * KTOT + it] = bi;
#pragma unroll
        for (int j = 0; j < 16; ++j)
            if (base + j == bi) v[j] = -INFINITY;
    }
}

// ---------------------------------------------------------------------------
// Flash attention R15 = R13 (XCD queues, 1 item/block, FETCH 9.9 MB) with
// ONE change: the prefetch-issue point.
// Post-mortem R13/R14: makespan = 33 tiles x 2.28 us INTRINSIC per-tile
// latency (tail runs contention-free); chain-shortening via split failed
// twice. The 2.28 us is explained by a compiler property [m97 asm]: hipcc
// emits s_waitcnt vmcnt(0) before EVERY s_barrier. R8/R13 issue
// prefetchKV(kt+1) immediately BEFORE the post-stage barrier, so the
// "prefetch" is fully drained at that barrier — its entire load latency
// sits on the serial chain every tile, overlapping with nothing.
// Fix: issue prefetchKV(kt+1) AFTER the post-stage barrier (first thing in
// the compute phase). The post-stage barrier then drains only LDS writes,
// and the loads fly under ~1 us of qk/softmax/pv before the next tile-top
// barrier drains them (by then complete).
//   old: barrier A | stage | prefetch | barrier B(drain=full lat) | compute
//   new: barrier A | stage | barrier B(ds only) | prefetch | compute
// Everything else identical to R13. GEMMs reverted to R9-exact.
// ---------------------------------------------------------------------------
__global__ __launch_bounds__(256) void attn_mfma(
        const __hip_bfloat16* __restrict__ qkv,
        const float* __restrict__ events,
        const int* __restrict__ topk,
        const float* __restrict__ amask,
        __hip_bfloat16* __restrict__ out,
        int* __restrict__ ctr) {
    const int tid = threadIdx.x;
    const int wave = tid >> 6, lane = tid & 63;
    const int quad = lane >> 4, lm = lane & 15;
    const int g = blockIdx.x & 7;      // XCD queue id (round-robin heuristic)

    const __hip_bfloat16* qf = qkv;
    const __hip_bfloat16* kf = qkv + 1024;
    const __hip_bfloat16* vf = qkv + 2048;

    __shared__ __hip_bfloat16 Ks[64 * LDK];
    __shared__ __hip_bfloat16 Vt[80 * LDK];   // [d][kcol]; rows 64..79 static (64=ones)
    __shared__ __hip_bfloat16 Ps[64 * LDK];
    __shared__ float colb[64];
    __shared__ float redb[4];
    __shared__ int sItem;

    const int va = tid & 31, vdc = tid >> 5;
    const int vtok0 = va * 2, vd0 = vdc * 8;

    // one-time init: finite Vt fill (stale x P==0 = 0 needs finite, not NaN)
    // and the static ones/zero rows.
    for (int i = tid * 8; i < 64 * LDK; i += 256 * 8)
        *(int4*)&Vt[i] = make_int4(0, 0, 0, 0);
    for (int i = tid; i < 16 * LDK; i += 256) {
        const int r = i / LDK;
        Vt[64 * LDK + i] = __float2bfloat16(r == 0 ? 1.0f : 0.0f);
    }

    for (;;) {
        __syncthreads();    // prev item's LDS readers done; also covers Vt init
        if (tid == 0) sItem = atomicAdd(&ctr[g], 1);
        __syncthreads();
        const int n = sItem;
        if (n >= QITEMS) break;

        // queue-local decode: qt descending (LPT), 4 streams per queue
        const int qt = 31 - (n >> 2);
        const int s  = g * 4 + (n & 3);          // stream id 0..31
        const int h  = 15 - (s >> 1);
        const int b  = s & 1;
        const int q0 = qt * 64;
        const float slope2 = __exp2(-0.5f * (float)(h + 1)) * 1.44269504f;  // log2 dom

        short8 pk[2], pv0, pv1;
        float pam = 1.f;
        auto prefetchKV = [&](int kt) {
            const __hip_bfloat16* ks = &kf[((size_t)(b * S_ + kt * 64)) * 3072 + h * 64];
#pragma unroll
            for (int u = 0; u < 2; ++u) {
                int c = tid * 2 + u, row = c >> 3, off = (c & 7) * 8;
                pk[u] = *(const short8*)&ks[(size_t)row * 3072 + off];
            }
            const __hip_bfloat16* v0 =
                &vf[((size_t)(b * S_ + kt * 64 + vtok0)) * 3072 + h * 64 + vd0];
            pv0 = *(const short8*)v0;
            pv1 = *(const short8*)(v0 + 3072);
            if (tid < 64) pam = amask[b * S_ + kt * 64 + tid];
        };
        auto stageKV = [&](int kt) {
#pragma unroll
            for (int u = 0; u < 2; ++u) {
                int c = tid * 2 + u, row = c >> 3, off = (c & 7) * 8;
                *(short8*)&Ks[row * LDK + off] = pk[u];
            }
#pragma unroll
            for (int j = 0; j < 8; ++j) {
                short2 pr; pr.x = pv0[j]; pr.y = pv1[j];
                *(short2*)&Vt[(vd0 + j) * LDK + vtok0] = pr;
            }
            if (tid < 64)
                colb[tid] = fmaf(-slope2, (float)(kt * 64 + tid), (1.f - pam) * NEG9);
        };

        prefetchKV(0);      // earliest possible issue; consumed by stageKV(0)

        // ---- Q fragments straight into registers ----
        short8 qa[2];
        {
            const __hip_bfloat16* qsrc =
                &qf[((size_t)(b * S_ + q0 + wave * 16 + lm)) * 3072 + h * 64 + quad * 8];
            qa[0] = *(const short8*)qsrc;
            qa[1] = *(const short8*)(qsrc + 32);
        }
        // memory tile (K rows 0..9; Vt cols 0..9; stale rest exactly masked:
        // Ks via cc>=KTOT -> NEG9, Vt via Ps == 0.0 exactly)
        if (tid < 80) {
            const int tok = tid >> 3, d0 = (tid & 7) * 8;
            const int ev = topk[b * KTOT + tok];
            const float* es = &events[(size_t)ev * 1024 + h * 64 + d0];
#pragma unroll
            for (int j = 0; j < 8; ++j) {
                __hip_bfloat16 x = __float2bfloat16(es[j]);
                Ks[tok * LDK + d0 + j] = x;
                Vt[(d0 + j) * LDK + tok] = x;
            }
        }

        float m_[4], mshift[4];
        f32x4 Oa[5];        // Oa[4] = softmax denominator column
#pragma unroll
        for (int i = 0; i < 4; ++i) {
            m_[i] = -INFINITY;
            mshift[i] = -slope2 * (float)(q0 + wave * 16 + quad * 4 + i);
        }
#pragma unroll
        for (int nt = 0; nt < 5; ++nt) Oa[nt] = (f32x4){0.f, 0.f, 0.f, 0.f};

        auto qk = [&](f32x4* sa) {
#pragma unroll
            for (int nt = 0; nt < 4; ++nt) sa[nt] = (f32x4){0.f, 0.f, 0.f, 0.f};
#pragma unroll
            for (int ks2 = 0; ks2 < 2; ++ks2) {
#pragma unroll
                for (int nt = 0; nt < 4; ++nt) {
                    short8 bk = *(const short8*)&Ks[(nt * 16 + lm) * LDK + ks2 * 32 + quad * 8];
                    sa[nt] = __builtin_amdgcn_mfma_f32_16x16x32_bf16(qa[ks2], bk, sa[nt], 0, 0, 0);
                }
            }
        };
        auto pv = [&]() {
#pragma unroll
            for (int ks2 = 0; ks2 < 2; ++ks2) {
                short8 ap = *(const short8*)&Ps[(wave * 16 + lm) * LDK + ks2 * 32 + quad * 8];
#pragma unroll
                for (int nt = 0; nt < 5; ++nt) {   // nt=4: ones column -> l
                    short8 bv = *(const short8*)&Vt[(nt * 16 + lm) * LDK + ks2 * 32 + quad * 8];
                    Oa[nt] = __builtin_amdgcn_mfma_f32_16x16x32_bf16(ap, bv, Oa[nt], 0, 0, 0);
                }
            }
        };

        auto softmax_online = [&](const f32x4* sa, int kt, bool diag) {
            float cb[4];
            if (kt >= 0) {
#pragma unroll
                for (int nt = 0; nt < 4; ++nt) cb[nt] = colb[nt * 16 + lm];
            }
#pragma unroll
            for (int i = 0; i < 4; ++i) {
                const int lr = wave * 16 + quad * 4 + i;
                const int rg = q0 + lr;
                float s2[4];
#pragma unroll
                for (int nt = 0; nt < 4; ++nt) {
                    const int cc = nt * 16 + lm;
                    if (kt < 0) {
                        s2[nt] = (cc < KTOT) ? fmaf(sa[nt][i], SC_, mshift[i]) : NEG9;
                    } else {
                        float v = fmaf(sa[nt][i], SC_, cb[nt]);
                        s2[nt] = (diag && kt * 64 + cc > rg) ? NEG9 : v;
                    }
                }
                float rmax = fmaxf(fmaxf(s2[0], s2[1]), fmaxf(s2[2], s2[3]));
#pragma unroll
                for (int off = 1; off < 16; off <<= 1)
                    rmax = fmaxf(rmax, __shfl_xor(rmax, off, 16));
                const float newm = fmaxf(m_[i], rmax);
                const float al = __exp2(m_[i] - newm);
                m_[i] = newm;
#pragma unroll
                for (int nt = 0; nt < 4; ++nt)
                    Ps[lr * LDK + nt * 16 + lm] = __float2bfloat16(__exp2(s2[nt] - newm));
#pragma unroll
                for (int nt = 0; nt < 5; ++nt)     // includes l-column
                    Oa[nt][i] *= al;
            }
        };

        auto softmax_fast = [&](const f32x4* sa, int cbase, bool diag) {
            float cb[4];
#pragma unroll
            for (int nt = 0; nt < 4; ++nt) cb[nt] = colb[nt * 16 + lm];
#pragma unroll
            for (int i = 0; i < 4; ++i) {
                const int lr = wave * 16 + quad * 4 + i;
                const float cm = m_[i];
                float p[4];
#pragma unroll
                for (int nt = 0; nt < 4; ++nt)
                    p[nt] = __exp2(fmaf(sa[nt][i], SC_, cb[nt]) - cm);
                if (diag) {
                    const int rg = q0 + lr;
#pragma unroll
                    for (int nt = 0; nt < 4; ++nt)
                        if (cbase + nt * 16 + lm > rg) p[nt] = 0.f;
                }
#pragma unroll
                for (int nt = 0; nt < 4; ++nt)
                    Ps[lr * LDK + nt * 16 + lm] = __float2bfloat16(p[nt]);
            }
        };

        // ---- memory tile (online) ----
        __syncthreads();            // publish mem tile
        {
            f32x4 sa[4];
            qk(sa);
            softmax_online(sa, -1, false);
            pv();
        }
        __syncthreads();            // mem readers done before stage overwrites
        // ---- kt = 0 (online); prefetch AFTER the barrier (R15 change) ----
        stageKV(0);
        __syncthreads();            // drains only ds writes
        if (qt >= 1) prefetchKV(1); // flies under kt0 compute
        {
            f32x4 sa[4];
            qk(sa);
            softmax_online(sa, 0, qt == 0);
            pv();
        }

        // ---- freeze max; block-min(m) -> exact-underflow cutoff ----
        int ktend = 0;
        if (qt >= 1) {
            float mloc = fminf(fminf(m_[0], m_[1]), fminf(m_[2], m_[3]));
#pragma unroll
            for (int off = 1; off < 64; off <<= 1)
                mloc = fminf(mloc, __shfl_xor(mloc, off, 64));
            if (lane == 0) redb[wave] = mloc;
            __syncthreads();        // redb visible + first-tile readers done
            const float mmin = fminf(fminf(redb[0], redb[1]), fminf(redb[2], redb[3]));
            ktend = min(qt, (int)((TH_ - mmin) / (64.f * slope2)));
        }
        for (int kt = 1; kt <= ktend; ++kt) {
            stageKV(kt);            // readers-done: freeze barrier (kt=1) or
                                    // loop-bottom barrier (kt>1)
            __syncthreads();        // drains only ds writes
            if (kt < ktend) prefetchKV(kt + 1);   // flies under this compute
            f32x4 sa[4];
            qk(sa);
            softmax_fast(sa, kt * 64, kt == qt);
            pv();
            __syncthreads();        // readers done before next stage;
                                    // also drains (now-complete) prefetch
        }

        // ---- epilogue: l lives in Oa[4] col 0 (lanes lm==0); broadcast ----
#pragma unroll
        for (int i = 0; i < 4; ++i) {
            const int lr = wave * 16 + quad * 4 + i;
            const float l = __shfl(Oa[4][i], (lane & 48));
            const float inv = 1.f / l;
            __hip_bfloat16* dst = &out[((size_t)(b * S_ + q0 + lr)) * 1024 + h * 64 + lm];
#pragma unroll
            for (int nt = 0; nt < 4; ++nt)
                dst[nt * 16] = __float2bfloat16(Oa[nt][i] * inv);
        }
    }
}

// ---------------------------------------------------------------------------
extern "C" void kernel_launch(void* const* d_in, const int* in_sizes, int n_in,
                              void* d_out, int out_size, void* d_ws, size_t ws_size,
                              hipStream_t stream) {
    const float* inputs = (const float*)d_in[0];
    const float* amask  = (const float*)d_in[1];
    const float* Wq     = (const float*)d_in[2];
    const float* Wk     = (const float*)d_in[3];
    const float* Wv     = (const float*)d_in[4];
    const float* Wo     = (const float*)d_in[5];
    const float* events = (const float*)d_in[6];
    float* out = (float*)d_out;

    // ws: Ax 8MB | Wt 8MB | qkv 24MB | ao 8MB | lk | sims | topk | ctr[8]
    __hip_bfloat16* Ax  = (__hip_bfloat16*)d_ws;
    __hip_bfloat16* Wt  = Ax + (size_t)NROW * 1024;
    __hip_bfloat16* qkv = Wt + (size_t)4096 * 1024;
    __hip_bfloat16* ao  = qkv + (size_t)NROW * 3072;
    float* lk   = (float*)(ao + (size_t)NROW * 1024);
    float* sims = lk + 2 * 1024;
    int* topk   = (int*)(sims + 2 * 1024);
    int* ctr    = topk + B_ * KTOT;

    dim3 blk(256);
    prep<<<3104, blk, 0, stream>>>(inputs, Wq, Wk, Wv, Wo, Ax, Wt, lk, ctr);
    sims_kernel<<<dim3(250, B_), blk, 0, stream>>>(lk, events, sims);
    topk10_kernel<<<B_, 64, 0, stream>>>(sims, topk);
    gemm_mfma<__hip_bfloat16><<<dim3(24, 32), blk, 0, stream>>>(Ax, Wt, qkv, 3072);
    attn_mfma<<<1024, blk, 0, stream>>>(qkv, events, topk, amask, ao, ctr);
    gemm_mfma64<float><<<dim3(8, 64), blk, 0, stream>>>(
        ao, Wt + (size_t)3072 * 1024, out, 1024);
}

// Round 9
// 231.557 us; speedup vs baseline: 1.1209x; 1.0151x over previous
//
#include <hip/hip_runtime.h>
#include <hip/hip_bf16.h>
#include <math.h>

// Problem constants
#define B_   2
#define S_   2048
#define DM_  1024
#define H_   16
#define HD_  64
#define MEM_ 1000
#define KTOT 10
#define NROW (B_ * S_)          // 4096
#define NEG9 (-1e9f)
#define LDK  72                 // bf16 row stride in attention LDS tiles
#define QITEMS 64               // items per XCD queue: 16 q-blocks x 4 streams
#define SC_  0.18033688f        // 0.125 * log2(e)  (QK scale, log2 domain)
#define TH_  170.238f           // 118 * log2(e)    (exact-underflow cutoff)

typedef __attribute__((ext_vector_type(8))) short short8;
typedef __attribute__((ext_vector_type(4))) float f32x4;

__device__ __forceinline__ float __exp2(float x) { return __builtin_amdgcn_exp2f(x); }

// async global->LDS, 16B per lane, dest = wave-uniform base + lane*16
__device__ __forceinline__ void gll16(const __hip_bfloat16* g, __hip_bfloat16* l) {
    __builtin_amdgcn_global_load_lds(
        (const __attribute__((address_space(1))) void*)g,
        (__attribute__((address_space(3))) void*)l, 16, 0, 0);
}

// ---------------------------------------------------------------------------
// prep: fused prologue (independent parts, branch on block range).
// ---------------------------------------------------------------------------
__global__ __launch_bounds__(256) void prep(const float* __restrict__ inputs,
                                            const float* __restrict__ Wq,
                                            const float* __restrict__ Wk,
                                            const float* __restrict__ Wv,
                                            const float* __restrict__ Wo,
                                            __hip_bfloat16* __restrict__ Ax,
                                            __hip_bfloat16* __restrict__ Wt,
                                            float* __restrict__ lk,
                                            int* __restrict__ ctr) {
    const int bx = blockIdx.x, tid = threadIdx.x;
    if (bx == 0 && tid < 8) ctr[tid] = 0;

    if (bx < 2048) {
        const size_t i = ((size_t)bx * 256 + tid) * 8;
        float4 a = *(const float4*)&inputs[i];
        float4 b = *(const float4*)&inputs[i + 4];
        alignas(16) __hip_bfloat16 t[8];
        t[0] = __float2bfloat16(a.x); t[1] = __float2bfloat16(a.y);
        t[2] = __float2bfloat16(a.z); t[3] = __float2bfloat16(a.w);
        t[4] = __float2bfloat16(b.x); t[5] = __float2bfloat16(b.y);
        t[6] = __float2bfloat16(b.z); t[7] = __float2bfloat16(b.w);
        *(short8*)&Ax[i] = *(short8*)t;
        return;
    }
    if (bx < 3072) {
        const int idx = bx - 2048;
        const int g = idx >> 8, rem = idx & 255;
        const float* W = (g == 0) ? Wq : (g == 1) ? Wk : (g == 2) ? Wv : Wo;
        const int n0 = (rem & 15) * 64, k0 = (rem >> 4) * 64;
        __shared__ float T[64][65];
        {
            const int r = tid >> 4, c4 = (tid & 15) * 4;
#pragma unroll
            for (int p = 0; p < 4; ++p) {
                float4 v = *(const float4*)&W[(size_t)(k0 + r + p * 16) * 1024 + n0 + c4];
                T[r + p * 16][c4 + 0] = v.x; T[r + p * 16][c4 + 1] = v.y;
                T[r + p * 16][c4 + 2] = v.z; T[r + p * 16][c4 + 3] = v.w;
            }
        }
        __syncthreads();
        {
            const int n = tid >> 3, off = (tid & 7) * 8;
#pragma unroll
            for (int p = 0; p < 2; ++p) {
                const int nn = n + p * 32;
                alignas(16) __hip_bfloat16 t[8];
#pragma unroll
                for (int j = 0; j < 8; ++j) t[j] = __float2bfloat16(T[off + j][nn]);
                *(short8*)&Wt[((size_t)(g * 1024 + n0 + nn)) * 1024 + k0 + off] = *(short8*)t;
            }
        }
        return;
    }
    {   // lastk: lk[b,:] = inputs[b, S-1, :] @ Wk (fp32)
        const int idx = bx - 3072;
        const int xblk = idx & 15, b = idx >> 4;
        const int cl = tid & 63;
        const int col = xblk * 64 + cl;
        const int kq = tid >> 6;
        __shared__ float xr[1024];
        __shared__ float part[4][64];
        for (int i = tid; i < 1024; i += 256)
            xr[i] = inputs[((size_t)(b * S_ + S_ - 1)) * 1024 + i];
        __syncthreads();
        float acc = 0.f;
#pragma unroll 4
        for (int k = kq * 256; k < kq * 256 + 256; ++k)
            acc += xr[k] * Wk[(size_t)k * 1024 + col];
        part[kq][cl] = acc;
        __syncthreads();
        if (tid < 64)
            lk[b * 1024 + xblk * 64 + tid] =
                part[0][tid] + part[1][tid] + part[2][tid] + part[3][tid];
    }
}

// ---------------------------------------------------------------------------
// bf16 MFMA GEMM, m97 structure (R9 exact).
// ---------------------------------------------------------------------------
__device__ __forceinline__ void store_out(__hip_bfloat16* p, float x) { *p = __float2bfloat16(x); }
__device__ __forceinline__ void store_out(float* p, float x) { *p = x; }

template <typename OutT>
__global__ __launch_bounds__(256) void gemm_mfma(const __hip_bfloat16* __restrict__ A,
                                                 const __hip_bfloat16* __restrict__ Bt,
                                                 OutT* __restrict__ C, int ldc) {
    __shared__ __hip_bfloat16 As[128 * 32];
    __shared__ __hip_bfloat16 Bs[128 * 32];
    const int tid = threadIdx.x;
    const int wave = tid >> 6, lane = tid & 63;
    const int quad = lane >> 4, lm = lane & 15;
    const int wr = wave >> 1, wc = wave & 1;
    const int m0 = blockIdx.y * 128, n0 = blockIdx.x * 128;

    const int r0 = tid >> 2, c0 = (tid & 3) * 8;
    const __hip_bfloat16* ga0 = &A[(size_t)(m0 + r0) * 1024 + c0];
    const __hip_bfloat16* ga1 = &A[(size_t)(m0 + 64 + r0) * 1024 + c0];
    const __hip_bfloat16* gb0 = &Bt[(size_t)(n0 + r0) * 1024 + c0];
    const __hip_bfloat16* gb1 = &Bt[(size_t)(n0 + 64 + r0) * 1024 + c0];
    __hip_bfloat16* la0 = &As[(wave * 64) * 8];
    __hip_bfloat16* la1 = &As[(256 + wave * 64) * 8];
    __hip_bfloat16* lb0 = &Bs[(wave * 64) * 8];
    __hip_bfloat16* lb1 = &Bs[(256 + wave * 64) * 8];

    f32x4 acc[4][4];
#pragma unroll
    for (int i = 0; i < 4; ++i)
#pragma unroll
        for (int j = 0; j < 4; ++j) acc[i][j] = (f32x4){0.f, 0.f, 0.f, 0.f};

    for (int k0 = 0; k0 < 1024; k0 += 32) {
        __syncthreads();
        gll16(ga0 + k0, la0);
        gll16(ga1 + k0, la1);
        gll16(gb0 + k0, lb0);
        gll16(gb1 + k0, lb1);
        __syncthreads();
        short8 af[4], bf4[4];
#pragma unroll
        for (int mt = 0; mt < 4; ++mt)
            af[mt] = *(const short8*)&As[(wr * 64 + mt * 16 + lm) * 32 + quad * 8];
#pragma unroll
        for (int nt = 0; nt < 4; ++nt)
            bf4[nt] = *(const short8*)&Bs[(wc * 64 + nt * 16 + lm) * 32 + quad * 8];
#pragma unroll
        for (int mt = 0; mt < 4; ++mt)
#pragma unroll
            for (int nt = 0; nt < 4; ++nt)
                acc[mt][nt] = __builtin_amdgcn_mfma_f32_16x16x32_bf16(
                    af[mt], bf4[nt], acc[mt][nt], 0, 0, 0);
    }
#pragma unroll
    for (int mt = 0; mt < 4; ++mt)
#pragma unroll
        for (int nt = 0; nt < 4; ++nt) {
            const int col = n0 + wc * 64 + nt * 16 + lm;
#pragma unroll
            for (int i = 0; i < 4; ++i) {
                const int row = m0 + wr * 64 + mt * 16 + quad * 4 + i;
                store_out(&C[(size_t)row * ldc + col], acc[mt][nt][i]);
            }
        }
}

// ---------------------------------------------------------------------------
// 64x128-tile variant for the out-projection GEMM (R9 exact, proven win).
// ---------------------------------------------------------------------------
template <typename OutT>
__global__ __launch_bounds__(256) void gemm_mfma64(const __hip_bfloat16* __restrict__ A,
                                                   const __hip_bfloat16* __restrict__ Bt,
                                                   OutT* __restrict__ C, int ldc) {
    __shared__ __hip_bfloat16 As[64 * 32];
    __shared__ __hip_bfloat16 Bs[128 * 32];
    const int tid = threadIdx.x;
    const int wave = tid >> 6, lane = tid & 63;
    const int quad = lane >> 4, lm = lane & 15;
    const int wr = wave >> 1, wc = wave & 1;
    const int m0 = blockIdx.y * 64, n0 = blockIdx.x * 128;

    const int r0 = tid >> 2, c0 = (tid & 3) * 8;
    const __hip_bfloat16* ga  = &A[(size_t)(m0 + r0) * 1024 + c0];
    const __hip_bfloat16* gb0 = &Bt[(size_t)(n0 + r0) * 1024 + c0];
    const __hip_bfloat16* gb1 = &Bt[(size_t)(n0 + 64 + r0) * 1024 + c0];
    __hip_bfloat16* la  = &As[(wave * 64) * 8];
    __hip_bfloat16* lb0 = &Bs[(wave * 64) * 8];
    __hip_bfloat16* lb1 = &Bs[(256 + wave * 64) * 8];

    f32x4 acc[2][4];
#pragma unroll
    for (int i = 0; i < 2; ++i)
#pragma unroll
        for (int j = 0; j < 4; ++j) acc[i][j] = (f32x4){0.f, 0.f, 0.f, 0.f};

    for (int k0 = 0; k0 < 1024; k0 += 32) {
        __syncthreads();
        gll16(ga + k0, la);
        gll16(gb0 + k0, lb0);
        gll16(gb1 + k0, lb1);
        __syncthreads();
        short8 af[2], bf4[4];
#pragma unroll
        for (int mt = 0; mt < 2; ++mt)
            af[mt] = *(const short8*)&As[(wr * 32 + mt * 16 + lm) * 32 + quad * 8];
#pragma unroll
        for (int nt = 0; nt < 4; ++nt)
            bf4[nt] = *(const short8*)&Bs[(wc * 64 + nt * 16 + lm) * 32 + quad * 8];
#pragma unroll
        for (int mt = 0; mt < 2; ++mt)
#pragma unroll
            for (int nt = 0; nt < 4; ++nt)
                acc[mt][nt] = __builtin_amdgcn_mfma_f32_16x16x32_bf16(
                    af[mt], bf4[nt], acc[mt][nt], 0, 0, 0);
    }
#pragma unroll
    for (int mt = 0; mt < 2; ++mt)
#pragma unroll
        for (int nt = 0; nt < 4; ++nt) {
            const int col = n0 + wc * 64 + nt * 16 + lm;
#pragma unroll
            for (int i = 0; i < 4; ++i) {
                const int row = m0 + wr * 32 + mt * 16 + quad * 4 + i;
                store_out(&C[(size_t)row * ldc + col], acc[mt][nt][i]);
            }
        }
}

// ---------------------------------------------------------------------------
// sims + topk (unchanged).
// ---------------------------------------------------------------------------
__global__ __launch_bounds__(256) void sims_kernel(const float* __restrict__ lk,
                                                   const float* __restrict__ events,
                                                   float* __restrict__ sims) {
    const int b = blockIdx.y;
    const int tid = threadIdx.x;
    const int wave = tid >> 6, lane = tid & 63;
    __shared__ float qv[1024];
    for (int i = tid; i < 1024; i += 256)
        qv[i] = lk[b * 1024 + i];
    __syncthreads();

    const int m = blockIdx.x * 4 + wave;
    if (m >= MEM_) return;
    const float* ev = &events[(size_t)m * 1024];
    float dot = 0.f, nrm = 0.f;
    for (int d = lane; d < 1024; d += 64) {
        float e = ev[d];
        dot += qv[d] * e;
        nrm += e * e;
    }
    for (int off = 32; off; off >>= 1) {
        dot += __shfl_down(dot, off);
        nrm += __shfl_down(nrm, off);
    }
    if (lane == 0) sims[b * 1024 + m] = dot / (sqrtf(nrm) + 1e-8f);
}

__global__ __launch_bounds__(64) void topk10_kernel(const float* __restrict__ sims,
                                                    int* __restrict__ topk) {
    const int b = blockIdx.x;
    const int lane = threadIdx.x;
    const int base = lane * 16;
    float v[16];
#pragma unroll
    for (int j = 0; j < 16; ++j) {
        const int m = base + j;
        v[j] = (m < MEM_) ? sims[b * 1024 + m] : -INFINITY;
    }
    for (int it = 0; it < KTOT; ++it) {
        float best = -INFINITY; int bi = 0x7fffffff;
#pragma unroll
        for (int j = 0; j < 16; ++j)
            if (v[j] > best) { best = v[j]; bi = base + j; }
        for (int off = 32; off; off >>= 1) {
            const float ob = __shfl_xor(best, off);
            const int   oi = __shfl_xor(bi, off);
            if (ob > best || (ob == best && oi < bi)) { best = ob; bi = oi; }
        }
        if (lane == 0) topk[b * KTOT + it] = bi;
#pragma unroll
        for (int j = 0; j < 16; ++j)
            if (base + j == bi) v[j] = -INFINITY;
    }
}

// ---------------------------------------------------------------------------
// Flash attention R16 = R13 engine + QBLK=128 (2x arithmetic intensity).
// Model (fits R8-R15): LDS-throughput-bound at CU level — per wave-tile
// ~20 ds_read_b128 + ~27 writes; every wave reads the FULL K/V tile but
// applies it to only 16 q-rows. Doubling q-rows per block (each wave 32
// rows via mt loop) halves LDS reads per unit work: K/V fragments read
// once per (nt,ks2), feed 2 MFMAs. Unlike R11 (172 VGPR, dual streams,
// lockstep merge): single KV stream, single softmax path, no merge,
// prefetch regs unchanged.
//  * 512 items (16 q-blocks x 32 streams); XCD queues (FETCH 9.9 MB
//    proven R13): 64 items/queue, qt2 descending (LPT). Grid 512 =
//    1 item/block, 2 blocks/CU (LDS 39.5 KB).
//  * causal: qt = 2*qt2+1 (last kv tile); diag masking for kt >= qt-1
//    (row-wise predicate unchanged; lower-half rows see tile qt fully
//    masked -> P=0 exact).
//  * frozen-max cutoff: mmin over all 128 rows (more conservative than
//    64-row case -> never skips a needed tile).
// Kept: single-buffer LDS, 2 barriers/tile, reg prefetch (R13 position),
// ones-column l-accum, Q-in-regs, log2-domain softmax, zero-once Vt.
// ---------------------------------------------------------------------------
__global__ __launch_bounds__(256) void attn_mfma(
        const __hip_bfloat16* __restrict__ qkv,
        const float* __restrict__ events,
        const int* __restrict__ topk,
        const float* __restrict__ amask,
        __hip_bfloat16* __restrict__ out,
        int* __restrict__ ctr) {
    const int tid = threadIdx.x;
    const int wave = tid >> 6, lane = tid & 63;
    const int quad = lane >> 4, lm = lane & 15;
    const int g = blockIdx.x & 7;      // XCD queue id (round-robin heuristic)

    const __hip_bfloat16* qf = qkv;
    const __hip_bfloat16* kf = qkv + 1024;
    const __hip_bfloat16* vf = qkv + 2048;

    __shared__ __hip_bfloat16 Ks[64 * LDK];
    __shared__ __hip_bfloat16 Vt[80 * LDK];    // [d][kcol]; rows 64..79 static (64=ones)
    __shared__ __hip_bfloat16 Ps[128 * LDK];   // 128 q-rows now
    __shared__ float colb[64];
    __shared__ float redb[4];
    __shared__ int sItem;

    const int va = tid & 31, vdc = tid >> 5;
    const int vtok0 = va * 2, vd0 = vdc * 8;

    // one-time init: finite Vt fill (stale x P==0 = 0 needs finite, not NaN)
    // and the static ones/zero rows.
    for (int i = tid * 8; i < 64 * LDK; i += 256 * 8)
        *(int4*)&Vt[i] = make_int4(0, 0, 0, 0);
    for (int i = tid; i < 16 * LDK; i += 256) {
        const int r = i / LDK;
        Vt[64 * LDK + i] = __float2bfloat16(r == 0 ? 1.0f : 0.0f);
    }

    for (;;) {
        __syncthreads();    // prev item's LDS readers done; also covers Vt init
        if (tid == 0) sItem = atomicAdd(&ctr[g], 1);
        __syncthreads();
        const int n = sItem;
        if (n >= QITEMS) break;

        // queue-local decode: qt2 descending (LPT), 4 streams per queue
        const int qt2 = 15 - (n >> 2);
        const int s  = g * 4 + (n & 3);          // stream id 0..31
        const int h  = 15 - (s >> 1);
        const int b  = s & 1;
        const int q0 = qt2 * 128;
        const int qt = 2 * qt2 + 1;              // last kv tile index
        const float slope2 = __exp2(-0.5f * (float)(h + 1)) * 1.44269504f;  // log2 dom

        short8 pk[2], pv0, pv1;
        float pam = 1.f;
        auto prefetchKV = [&](int kt) {
            const __hip_bfloat16* ks = &kf[((size_t)(b * S_ + kt * 64)) * 3072 + h * 64];
#pragma unroll
            for (int u = 0; u < 2; ++u) {
                int c = tid * 2 + u, row = c >> 3, off = (c & 7) * 8;
                pk[u] = *(const short8*)&ks[(size_t)row * 3072 + off];
            }
            const __hip_bfloat16* v0 =
                &vf[((size_t)(b * S_ + kt * 64 + vtok0)) * 3072 + h * 64 + vd0];
            pv0 = *(const short8*)v0;
            pv1 = *(const short8*)(v0 + 3072);
            if (tid < 64) pam = amask[b * S_ + kt * 64 + tid];
        };
        auto stageKV = [&](int kt) {
#pragma unroll
            for (int u = 0; u < 2; ++u) {
                int c = tid * 2 + u, row = c >> 3, off = (c & 7) * 8;
                *(short8*)&Ks[row * LDK + off] = pk[u];
            }
#pragma unroll
            for (int j = 0; j < 8; ++j) {
                short2 pr; pr.x = pv0[j]; pr.y = pv1[j];
                *(short2*)&Vt[(vd0 + j) * LDK + vtok0] = pr;
            }
            if (tid < 64)
                colb[tid] = fmaf(-slope2, (float)(kt * 64 + tid), (1.f - pam) * NEG9);
        };

        prefetchKV(0);      // earliest possible issue; consumed by stageKV(0)

        // ---- Q fragments (2 row-tiles per wave) straight into registers ----
        short8 qa[2][2];
#pragma unroll
        for (int mt = 0; mt < 2; ++mt) {
            const __hip_bfloat16* qsrc =
                &qf[((size_t)(b * S_ + q0 + wave * 32 + mt * 16 + lm)) * 3072 + h * 64 + quad * 8];
            qa[mt][0] = *(const short8*)qsrc;
            qa[mt][1] = *(const short8*)(qsrc + 32);
        }
        // memory tile (K rows 0..9; Vt cols 0..9; stale rest exactly masked)
        if (tid < 80) {
            const int tok = tid >> 3, d0 = (tid & 7) * 8;
            const int ev = topk[b * KTOT + tok];
            const float* es = &events[(size_t)ev * 1024 + h * 64 + d0];
#pragma unroll
            for (int j = 0; j < 8; ++j) {
                __hip_bfloat16 x = __float2bfloat16(es[j]);
                Ks[tok * LDK + d0 + j] = x;
                Vt[(d0 + j) * LDK + tok] = x;
            }
        }

        float m_[2][4], mshift[2][4];
        f32x4 Oa[2][5];     // Oa[mt][4] = softmax denominator column
#pragma unroll
        for (int mt = 0; mt < 2; ++mt)
#pragma unroll
            for (int i = 0; i < 4; ++i) {
                m_[mt][i] = -INFINITY;
                mshift[mt][i] = -slope2 * (float)(q0 + wave * 32 + mt * 16 + quad * 4 + i);
            }
#pragma unroll
        for (int mt = 0; mt < 2; ++mt)
#pragma unroll
            for (int nt = 0; nt < 5; ++nt) Oa[mt][nt] = (f32x4){0.f, 0.f, 0.f, 0.f};

        auto qk = [&](f32x4 (&sa)[2][4]) {
#pragma unroll
            for (int mt = 0; mt < 2; ++mt)
#pragma unroll
                for (int nt = 0; nt < 4; ++nt) sa[mt][nt] = (f32x4){0.f, 0.f, 0.f, 0.f};
#pragma unroll
            for (int ks2 = 0; ks2 < 2; ++ks2) {
#pragma unroll
                for (int nt = 0; nt < 4; ++nt) {
                    short8 bk = *(const short8*)&Ks[(nt * 16 + lm) * LDK + ks2 * 32 + quad * 8];
#pragma unroll
                    for (int mt = 0; mt < 2; ++mt)      // K frag reused 2x
                        sa[mt][nt] = __builtin_amdgcn_mfma_f32_16x16x32_bf16(
                            qa[mt][ks2], bk, sa[mt][nt], 0, 0, 0);
                }
            }
        };
        auto pv = [&]() {
#pragma unroll
            for (int ks2 = 0; ks2 < 2; ++ks2) {
                short8 ap[2];
#pragma unroll
                for (int mt = 0; mt < 2; ++mt)
                    ap[mt] = *(const short8*)&Ps[(wave * 32 + mt * 16 + lm) * LDK + ks2 * 32 + quad * 8];
#pragma unroll
                for (int nt = 0; nt < 5; ++nt) {   // nt=4: ones column -> l
                    short8 bv = *(const short8*)&Vt[(nt * 16 + lm) * LDK + ks2 * 32 + quad * 8];
#pragma unroll
                    for (int mt = 0; mt < 2; ++mt)  // V frag reused 2x
                        Oa[mt][nt] = __builtin_amdgcn_mfma_f32_16x16x32_bf16(
                            ap[mt], bv, Oa[mt][nt], 0, 0, 0);
                }
            }
        };

        auto softmax_online = [&](const f32x4 (&sa)[2][4], int kt, bool diag) {
            float cb[4];
            if (kt >= 0) {
#pragma unroll
                for (int nt = 0; nt < 4; ++nt) cb[nt] = colb[nt * 16 + lm];
            }
#pragma unroll
            for (int mt = 0; mt < 2; ++mt)
#pragma unroll
                for (int i = 0; i < 4; ++i) {
                    const int lr = wave * 32 + mt * 16 + quad * 4 + i;
                    const int rg = q0 + lr;
                    float s2[4];
#pragma unroll
                    for (int nt = 0; nt < 4; ++nt) {
                        const int cc = nt * 16 + lm;
                        if (kt < 0) {
                            s2[nt] = (cc < KTOT) ? fmaf(sa[mt][nt][i], SC_, mshift[mt][i]) : NEG9;
                        } else {
                            float v = fmaf(sa[mt][nt][i], SC_, cb[nt]);
                            s2[nt] = (diag && kt * 64 + cc > rg) ? NEG9 : v;
                        }
                    }
                    float rmax = fmaxf(fmaxf(s2[0], s2[1]), fmaxf(s2[2], s2[3]));
#pragma unroll
                    for (int off = 1; off < 16; off <<= 1)
                        rmax = fmaxf(rmax, __shfl_xor(rmax, off, 16));
                    const float newm = fmaxf(m_[mt][i], rmax);
                    const float al = __exp2(m_[mt][i] - newm);
                    m_[mt][i] = newm;
#pragma unroll
                    for (int nt = 0; nt < 4; ++nt)
                        Ps[lr * LDK + nt * 16 + lm] = __float2bfloat16(__exp2(s2[nt] - newm));
#pragma unroll
                    for (int nt = 0; nt < 5; ++nt)     // includes l-column
                        Oa[mt][nt][i] *= al;
                }
        };

        auto softmax_fast = [&](const f32x4 (&sa)[2][4], int cbase, bool diag) {
            float cb[4];
#pragma unroll
            for (int nt = 0; nt < 4; ++nt) cb[nt] = colb[nt * 16 + lm];
#pragma unroll
            for (int mt = 0; mt < 2; ++mt)
#pragma unroll
                for (int i = 0; i < 4; ++i) {
                    const int lr = wave * 32 + mt * 16 + quad * 4 + i;
                    const float cm = m_[mt][i];
                    float p[4];
#pragma unroll
                    for (int nt = 0; nt < 4; ++nt)
                        p[nt] = __exp2(fmaf(sa[mt][nt][i], SC_, cb[nt]) - cm);
                    if (diag) {
                        const int rg = q0 + lr;
#pragma unroll
                        for (int nt = 0; nt < 4; ++nt)
                            if (cbase + nt * 16 + lm > rg) p[nt] = 0.f;
                    }
#pragma unroll
                    for (int nt = 0; nt < 4; ++nt)
                        Ps[lr * LDK + nt * 16 + lm] = __float2bfloat16(p[nt]);
                }
        };

        // ---- memory tile (online) ----
        __syncthreads();            // publish mem tile
        {
            f32x4 sa[2][4];
            qk(sa);
            softmax_online(sa, -1, false);
            pv();
        }
        __syncthreads();            // mem readers done before stage overwrites
        // ---- kt = 0 (online) ----
        stageKV(0);
        if (qt >= 1) prefetchKV(1);
        __syncthreads();
        {
            f32x4 sa[2][4];
            qk(sa);
            softmax_online(sa, 0, 0 >= qt - 1);
            pv();
        }

        // ---- freeze max; block-min(m) -> exact-underflow cutoff ----
        int ktend = 0;
        {
            float mloc = fminf(fminf(m_[0][0], m_[0][1]), fminf(m_[0][2], m_[0][3]));
            mloc = fminf(mloc, fminf(fminf(m_[1][0], m_[1][1]), fminf(m_[1][2], m_[1][3])));
#pragma unroll
            for (int off = 1; off < 64; off <<= 1)
                mloc = fminf(mloc, __shfl_xor(mloc, off, 64));
            if (lane == 0) redb[wave] = mloc;
            __syncthreads();        // redb visible + first-tile readers done
            const float mmin = fminf(fminf(redb[0], redb[1]), fminf(redb[2], redb[3]));
            ktend = min(qt, (int)((TH_ - mmin) / (64.f * slope2)));
        }
        for (int kt = 1; kt <= ktend; ++kt) {
            stageKV(kt);
            if (kt < ktend) prefetchKV(kt + 1);
            __syncthreads();
            f32x4 sa[2][4];
            qk(sa);
            softmax_fast(sa, kt * 64, kt >= qt - 1);
            pv();
            __syncthreads();        // readers done before next stage
        }

        // ---- epilogue: l lives in Oa[mt][4] col 0 (lanes lm==0); broadcast ----
#pragma unroll
        for (int mt = 0; mt < 2; ++mt)
#pragma unroll
            for (int i = 0; i < 4; ++i) {
                const int lr = wave * 32 + mt * 16 + quad * 4 + i;
                const float l = __shfl(Oa[mt][4][i], (lane & 48));
                const float inv = 1.f / l;
                __hip_bfloat16* dst =
                    &out[((size_t)(b * S_ + q0 + lr)) * 1024 + h * 64 + lm];
#pragma unroll
                for (int nt = 0; nt < 4; ++nt)
                    dst[nt * 16] = __float2bfloat16(Oa[mt][nt][i] * inv);
            }
    }
}

// ---------------------------------------------------------------------------
extern "C" void kernel_launch(void* const* d_in, const int* in_sizes, int n_in,
                              void* d_out, int out_size, void* d_ws, size_t ws_size,
                              hipStream_t stream) {
    const float* inputs = (const float*)d_in[0];
    const float* amask  = (const float*)d_in[1];
    const float* Wq     = (const float*)d_in[2];
    const float* Wk     = (const float*)d_in[3];
    const float* Wv     = (const float*)d_in[4];
    const float* Wo     = (const float*)d_in[5];
    const float* events = (const float*)d_in[6];
    float* out = (float*)d_out;

    // ws: Ax 8MB | Wt 8MB | qkv 24MB | ao 8MB | lk | sims | topk | ctr[8]
    __hip_bfloat16* Ax  = (__hip_bfloat16*)d_ws;
    __hip_bfloat16* Wt  = Ax + (size_t)NROW * 1024;
    __hip_bfloat16* qkv = Wt + (size_t)4096 * 1024;
    __hip_bfloat16* ao  = qkv + (size_t)NROW * 3072;
    float* lk   = (float*)(ao + (size_t)NROW * 1024);
    float* sims = lk + 2 * 1024;
    int* topk   = (int*)(sims + 2 * 1024);
    int* ctr    = topk + B_ * KTOT;

    dim3 blk(256);
    prep<<<3104, blk, 0, stream>>>(inputs, Wq, Wk, Wv, Wo, Ax, Wt, lk, ctr);
    sims_kernel<<<dim3(250, B_), blk, 0, stream>>>(lk, events, sims);
    topk10_kernel<<<B_, 64, 0, stream>>>(sims, topk);
    gemm_mfma<__hip_bfloat16><<<dim3(24, 32), blk, 0, stream>>>(Ax, Wt, qkv, 3072);
    attn_mfma<<<512, blk, 0, stream>>>(qkv, events, topk, amask, ao, ctr);
    gemm_mfma64<float><<<dim3(8, 64), blk, 0, stream>>>(
        ao, Wt + (size_t)3072 * 1024, out, 1024);
}